// Round 7
// baseline (211.417 us; speedup 1.0000x reference)
//
#include <hip/hip_runtime.h>
#include <hip/hip_bf16.h>
#include <stdint.h>

// MHA: B=4, S=2048, D_MODEL=1024, H=16, hd=64.
// Interface: fp32 in / fp32 out. Internal compute: bf16 MFMA.

#define B_  4
#define S_  2048
#define DM  1024
#define H_  16
#define HD  64
#define BH  (B_ * H_)

typedef __attribute__((ext_vector_type(8))) short short8;
typedef __attribute__((ext_vector_type(4))) float f32x4;

union U8 { short8 v; ushort u[8]; };

__device__ __forceinline__ ushort f2bf(float f) {
  union { float f; uint32_t i; } x; x.f = f;
  uint32_t r = (x.i + 0x7FFFu + ((x.i >> 16) & 1u)) >> 16;
  return (ushort)r;
}

// packed f32x2 -> bf16x2 (RNE), gfx950 hw convert; no builtin exists (m240)
__device__ __forceinline__ uint32_t cvt_pk_bf16(float a, float b) {
  uint32_t r;
  asm("v_cvt_pk_bf16_f32 %0, %1, %2" : "=v"(r) : "v"(a), "v"(b));
  return r;
}

// raw 2^x (v_exp_f32 IS exp2)
__device__ __forceinline__ float exp2f_fast(float x) {
  float r;
  asm("v_exp_f32 %0, %1" : "=v"(r) : "v"(x));
  return r;
}

__device__ __forceinline__ void glds16(const ushort* g, ushort* l) {
  __builtin_amdgcn_global_load_lds(
      (const __attribute__((address_space(1))) void*)g,
      (__attribute__((address_space(3))) void*)l, 16, 0, 0);
}

#define MAX3(a, b, c) fmaxf(fmaxf((a), (b)), (c))

// ---------------- weight ingest: fp32 [1024][1024] -> bf16 transposed (4 fused) ----------------
__global__ __launch_bounds__(256) void transposeW4(
    const float* __restrict__ s0, const float* __restrict__ s1,
    const float* __restrict__ s2, const float* __restrict__ s3,
    ushort* __restrict__ dbase) {
  __shared__ __align__(16) ushort tile[64][72];
  const int t = threadIdx.x;
  const int bx = blockIdx.x & 15;   // src col block
  const int by = blockIdx.x >> 4;   // src row block
  const int wsel = blockIdx.y;
  const float* src = wsel == 0 ? s0 : (wsel == 1 ? s1 : (wsel == 2 ? s2 : s3));
  ushort* dst = dbase + (size_t)wsel * 1024 * 1024;
#pragma unroll
  for (int i = 0; i < 2; i++) {
    int e = (i * 256 + t) * 8;
    int r = e >> 6, c = e & 63;
    const float* sp = src + (size_t)(by * 64 + r) * 1024 + bx * 64 + c;
    float4 a = ((const float4*)sp)[0];
    float4 b = ((const float4*)sp)[1];
    tile[r][c + 0] = f2bf(a.x); tile[r][c + 1] = f2bf(a.y);
    tile[r][c + 2] = f2bf(a.z); tile[r][c + 3] = f2bf(a.w);
    tile[r][c + 4] = f2bf(b.x); tile[r][c + 5] = f2bf(b.y);
    tile[r][c + 6] = f2bf(b.z); tile[r][c + 7] = f2bf(b.w);
  }
  __syncthreads();
#pragma unroll
  for (int i = 0; i < 2; i++) {
    int e = (i * 256 + t) * 8;
    int r = e >> 6, c = e & 63;
    U8 st;
#pragma unroll
    for (int j = 0; j < 8; j++) st.u[j] = tile[c + j][r];
    *(short8*)(dst + (size_t)(bx * 64 + r) * 1024 + by * 64 + c) = st.v;
  }
}

// ---------------- GEMM: C[M][N] = A[M][K] * BT[N][K]^T + bias ----------------
// SEPARATE launches per projection (R6 post-mortem: fusing QKV via grid.z made the
// per-XCD live B-panel set 24x256KB = 6MB > 4MB L2 -> glds16(B) L2-missed ->
// barrier vmcnt(0) drains at L3 latency; 127us vs 3x27us unfused).
// AFP32: A is fp32, reg-staged + cvt_pk, with NEXT-ITER PREFETCH: the 4 float4
//   loads for k+1 issue after the post-stage barrier so the barrier's vmcnt(0)
//   drain excludes them; their ~500cy latency hides under ds_read+MFMA.
// CMODE 0: fp32 row-major out.
// CMODE 1: bf16 head-split [B][H][S][64] out.
// CMODE 2: bf16 V^T [BH][64][S] out with 8B-subchunk swizzle (phys = logical ^ (d&15))
//          baked per 64-col block -> attn stages vbuf with a LINEAR copy.
template<int AFP32, int CMODE>
__global__ __launch_bounds__(256, 2) void gemm_bt(
    const void* __restrict__ Ap, const ushort* __restrict__ BT,
    const float* __restrict__ bias, void* __restrict__ Cp,
    int M, int N, int K, float oscale) {
  __shared__ __align__(16) ushort lA[128 * 32];
  __shared__ __align__(16) ushort lB[128 * 32];
  const int t = threadIdx.x;
  const int lane = t & 63;
  const int w = t >> 6;
  const int wr = w >> 1, wc = w & 1;
  const int bm0 = blockIdx.x * 128;
  const int bn0 = blockIdx.y * 128;
  f32x4 acc[4][4] = {};

  const int arow = t >> 2;           // 0..63
  const int acol = (t & 3) * 8;      // element offset within 32-wide K slab
  const ushort* gA0 = (const ushort*)Ap + (size_t)(bm0 + arow) * K + acol;
  const ushort* gA1 = (const ushort*)Ap + (size_t)(bm0 + 64 + arow) * K + acol;
  const float*  fA0 = (const float*)Ap + (size_t)(bm0 + arow) * K + acol;
  const float*  fA1 = (const float*)Ap + (size_t)(bm0 + 64 + arow) * K + acol;
  const ushort* gB0 = BT + (size_t)(bn0 + arow) * K + acol;
  const ushort* gB1 = BT + (size_t)(bn0 + 64 + arow) * K + acol;

  float4 px0, px1, py0, py1;
  if constexpr (AFP32) {
    px0 = ((const float4*)fA0)[0];
    px1 = ((const float4*)fA0)[1];
    py0 = ((const float4*)fA1)[0];
    py1 = ((const float4*)fA1)[1];
  }

  for (int k0 = 0; k0 < K; k0 += 32) {
    if (k0) __syncthreads();
    if constexpr (AFP32) {
      union { short8 v; uint32_t u[4]; } s0, s1;
      s0.u[0] = cvt_pk_bf16(px0.x, px0.y); s0.u[1] = cvt_pk_bf16(px0.z, px0.w);
      s0.u[2] = cvt_pk_bf16(px1.x, px1.y); s0.u[3] = cvt_pk_bf16(px1.z, px1.w);
      s1.u[0] = cvt_pk_bf16(py0.x, py0.y); s1.u[1] = cvt_pk_bf16(py0.z, py0.w);
      s1.u[2] = cvt_pk_bf16(py1.x, py1.y); s1.u[3] = cvt_pk_bf16(py1.z, py1.w);
      *(short8*)&lA[t * 8] = s0.v;
      *(short8*)&lA[2048 + t * 8] = s1.v;
    } else {
      glds16(gA0 + k0, &lA[t * 8]);
      glds16(gA1 + k0, &lA[2048 + t * 8]);
    }
    glds16(gB0 + k0, &lB[t * 8]);
    glds16(gB1 + k0, &lB[2048 + t * 8]);
    __syncthreads();
    // prefetch next A slab AFTER the barrier: excluded from the vmcnt(0) drain,
    // latency hides under ds_read + MFMA below; consumed after next barrier.
    if constexpr (AFP32) {
      if (k0 + 32 < K) {
        px0 = ((const float4*)(fA0 + k0 + 32))[0];
        px1 = ((const float4*)(fA0 + k0 + 32))[1];
        py0 = ((const float4*)(fA1 + k0 + 32))[0];
        py1 = ((const float4*)(fA1 + k0 + 32))[1];
      }
    }
    short8 af[4], bf[4];
#pragma unroll
    for (int i = 0; i < 4; i++)
      af[i] = *(const short8*)&lA[(wr * 64 + i * 16 + (lane & 15)) * 32 + (lane >> 4) * 8];
#pragma unroll
    for (int j = 0; j < 4; j++)
      bf[j] = *(const short8*)&lB[(wc * 64 + j * 16 + (lane & 15)) * 32 + (lane >> 4) * 8];
#pragma unroll
    for (int i = 0; i < 4; i++)
#pragma unroll
      for (int j = 0; j < 4; j++)
        acc[i][j] = __builtin_amdgcn_mfma_f32_16x16x32_bf16(af[i], bf[j], acc[i][j], 0, 0, 0);
  }

  const int r0 = (lane >> 4) * 4;
#pragma unroll
  for (int j = 0; j < 4; j++) {
    const int col = bn0 + wc * 64 + j * 16 + (lane & 15);
    const float bc = bias[col];
#pragma unroll
    for (int i = 0; i < 4; i++) {
      const int row = bm0 + wr * 64 + i * 16 + r0;   // row % 4 == 0
      if constexpr (CMODE == 2) {
        // V^T swizzled: 4 consecutive s = one 8B sub-chunk
        const int bb = row >> 11, s = row & 2047;
        const int hh = col >> 6, d = col & 63;
        uint32_t p01 = cvt_pk_bf16((acc[i][j][0] + bc) * oscale, (acc[i][j][1] + bc) * oscale);
        uint32_t p23 = cvt_pk_bf16((acc[i][j][2] + bc) * oscale, (acc[i][j][3] + bc) * oscale);
        ushort* vtb = (ushort*)Cp + (((size_t)bb * H_ + hh) * HD + d) * (size_t)S_;
        const int sc = (s & 63) >> 2;                // logical 8B sub-chunk in 64-col block
        *(uint2*)(vtb + (s & ~63) + ((sc ^ (d & 15)) << 2)) = (uint2){p01, p23};
      } else {
#pragma unroll
        for (int r = 0; r < 4; r++) {
          float val = (acc[i][j][r] + bc) * oscale;
          if constexpr (CMODE == 0) {
            ((float*)Cp)[(size_t)(row + r) * N + col] = val;
          } else {
            int rr = row + r;
            int b = rr >> 11, s = rr & 2047;
            int h = col >> 6, d = col & 63;
            ((ushort*)Cp)[(((size_t)b * H_ + h) * S_ + s) * HD + d] = f2bf(val);
          }
        }
      }
    }
  }
}

// ---------------- flash attention (swapped-QK^T, in-register P, 64 q-rows/wave) ----------------
// R6 measured: ~36us (was 113) — the 4-qi LDS amortization fix (R5 post-mortem:
// LDS-read-BW bound at 256KB/CU/tile-round; now 128KB over 2x work). DO NOT TOUCH.
// q,k: bf16 [BH][S][64] (q pre-scaled by log2(e)/8), vt: bf16 [BH][64][S] 8B-swizzled,
// o: bf16 [B][S][1024]
__global__ __launch_bounds__(256, 2) void attn(
    const ushort* __restrict__ q, const ushort* __restrict__ k,
    const ushort* __restrict__ vt, ushort* __restrict__ o) {
  __shared__ __align__(16) ushort kbuf[2][4096];
  __shared__ __align__(16) ushort vbuf[2][4096];
  const int t = threadIdx.x;
  const int lane = t & 63;
  const int w = t >> 6;
  // XCD-bijective swizzle: 512 blocks, 8 q-tiles/head -> each XCD owns 8 whole heads
  const int L = ((blockIdx.x & 7) << 6) + (blockIdx.x >> 3);
  const int bh = L >> 3;
  const int q0 = (L & 7) * 256;
  const int b = bh >> 4, h = bh & 15;
  const int l15 = lane & 15;
  const int g = lane >> 4;

  const ushort* kbase  = k  + (size_t)bh * S_ * HD;
  const ushort* vtbase = vt + (size_t)bh * HD * S_;

  // Q fragments: 64 rows per wave (4 x 16), hd=64 in two x-slabs (MFMA B operand)
  short8 qf[4][2];
#pragma unroll
  for (int qi = 0; qi < 4; qi++) {
    const ushort* qp = q + ((size_t)bh * S_ + q0 + w * 64 + qi * 16 + l15) * HD + g * 8;
    qf[qi][0] = *(const short8*)qp;
    qf[qi][1] = *(const short8*)(qp + 32);
  }

  // ones A-fragment for l accumulation (bf16 1.0 = 0x3F80)
  short8 onesf;
#pragma unroll
  for (int j = 0; j < 8; j++) onesf[j] = (short)0x3F80;

  float m_r[4] = {-1e30f, -1e30f, -1e30f, -1e30f};
  f32x4 l_acc[4];
  f32x4 o_acc[4][4];
#pragma unroll
  for (int qi = 0; qi < 4; qi++) {
    l_acc[qi] = (f32x4){0.f, 0.f, 0.f, 0.f};
#pragma unroll
    for (int cb = 0; cb < 4; cb++) o_acc[qi][cb] = (f32x4){0.f, 0.f, 0.f, 0.f};
  }

  // V-read sub-chunk offsets (ushort units), loop/cb-invariant: (8ks+g+{0,4}) ^ l15
  int vo[2][2];
#pragma unroll
  for (int ks = 0; ks < 2; ks++) {
    vo[ks][0] = ((8 * ks + g) ^ l15) << 2;
    vo[ks][1] = ((8 * ks + 4 + g) ^ l15) << 2;
  }

  // stage one 64-kv tile: K with XOR-swizzled source (16B chunks), V linear (pre-swizzled in vt)
  auto STAGE = [&](int sel_, int kv0) {
#pragma unroll
    for (int i = 0; i < 2; i++) {
      int c = i * 256 + t;            // 16B-chunk index, 512 chunks per tile
      int row = c >> 3;
      int cc = (c & 7) ^ (row & 7);   // pre-swizzled source chunk (K only)
      glds16(kbase + (size_t)(kv0 + row) * HD + cc * 8, &kbuf[sel_][c * 8]);
      glds16(vtbase + (size_t)row * S_ + kv0 + (c & 7) * 8, &vbuf[sel_][c * 8]);
    }
  };

  STAGE(0, 0);
  __syncthreads();

  int sel = 0;
  for (int kv0 = 0; kv0 < S_; kv0 += 64, sel ^= 1) {
    if (kv0 + 64 < S_) STAGE(sel ^ 1, kv0 + 64);

    // ---- S^T = K (Q*log2e/8)^T : lane holds k-rows (4g+r per cb) of q-col l15 ----
    f32x4 sc[4][4];
#pragma unroll
    for (int qi = 0; qi < 4; qi++)
#pragma unroll
      for (int cb = 0; cb < 4; cb++) sc[qi][cb] = (f32x4){0.f, 0.f, 0.f, 0.f};
    __builtin_amdgcn_s_setprio(1);
#pragma unroll
    for (int cb = 0; cb < 4; cb++) {
      const int row = cb * 16 + l15;
      const int r7 = row & 7;
      short8 kf0 = *(const short8*)&kbuf[sel][(row * 8 + (g ^ r7)) * 8];
      short8 kf1 = *(const short8*)&kbuf[sel][(row * 8 + ((4 + g) ^ r7)) * 8];
#pragma unroll
      for (int qi = 0; qi < 4; qi++) {
        sc[qi][cb] = __builtin_amdgcn_mfma_f32_16x16x32_bf16(kf0, qf[qi][0], sc[qi][cb], 0, 0, 0);
        sc[qi][cb] = __builtin_amdgcn_mfma_f32_16x16x32_bf16(kf1, qf[qi][1], sc[qi][cb], 0, 0, 0);
      }
    }
    __builtin_amdgcn_s_setprio(0);

    // ---- softmax per qi (optimistic exp; shfl max off critical path) ----
    union PB { short8 v; uint32_t u[4]; } pbq[4][2];
#pragma unroll
    for (int qi = 0; qi < 4; qi++) {
      const float m = m_r[qi];
#pragma unroll
      for (int cb = 0; cb < 4; cb++) {
        float p0 = exp2f_fast(sc[qi][cb][0] - m);
        float p1 = exp2f_fast(sc[qi][cb][1] - m);
        float p2 = exp2f_fast(sc[qi][cb][2] - m);
        float p3 = exp2f_fast(sc[qi][cb][3] - m);
        pbq[qi][cb >> 1].u[(cb & 1) * 2 + 0] = cvt_pk_bf16(p0, p1);
        pbq[qi][cb >> 1].u[(cb & 1) * 2 + 1] = cvt_pk_bf16(p2, p3);
      }
      // tile max (in-lane max3 tree + verified shfl_xor cross-lane)
      float z0 = MAX3(sc[qi][0][0], sc[qi][0][1], sc[qi][0][2]);
      float z1 = MAX3(sc[qi][0][3], sc[qi][1][0], sc[qi][1][1]);
      float z2 = MAX3(sc[qi][1][2], sc[qi][1][3], sc[qi][2][0]);
      float z3 = MAX3(sc[qi][2][1], sc[qi][2][2], sc[qi][2][3]);
      float z4 = MAX3(sc[qi][3][0], sc[qi][3][1], sc[qi][3][2]);
      float mx = MAX3(MAX3(z0, z1, z2), fmaxf(z3, z4), sc[qi][3][3]);
      mx = fmaxf(mx, __shfl_xor(mx, 16));
      mx = fmaxf(mx, __shfl_xor(mx, 32));

      // rare path: max grew past m + 8*log2e (always taken on first tile)
      const float THR = 11.5415603f;  // 8 * log2(e)
      if (!__all(mx <= m + THR)) {
        float mn = fmaxf(m, mx);
        float fct = exp2f_fast(m - mn);
        m_r[qi] = mn;
        l_acc[qi] *= fct;
#pragma unroll
        for (int cb = 0; cb < 4; cb++)
#pragma unroll
          for (int r = 0; r < 4; r++) o_acc[qi][cb][r] *= fct;
#pragma unroll
        for (int cb = 0; cb < 4; cb++) {
          float p0 = exp2f_fast(sc[qi][cb][0] - mn);
          float p1 = exp2f_fast(sc[qi][cb][1] - mn);
          float p2 = exp2f_fast(sc[qi][cb][2] - mn);
          float p3 = exp2f_fast(sc[qi][cb][3] - mn);
          pbq[qi][cb >> 1].u[(cb & 1) * 2 + 0] = cvt_pk_bf16(p0, p1);
          pbq[qi][cb >> 1].u[(cb & 1) * 2 + 1] = cvt_pk_bf16(p2, p3);
        }
      }
    }

    // ---- O^T += V^T P^T, l += 1.P ; vv loaded once per (ks,cb), reused by 4 qi ----
    __builtin_amdgcn_s_setprio(1);
#pragma unroll
    for (int ks = 0; ks < 2; ks++) {
#pragma unroll
      for (int qi = 0; qi < 4; qi++)
        l_acc[qi] = __builtin_amdgcn_mfma_f32_16x16x32_bf16(onesf, pbq[qi][ks].v, l_acc[qi], 0, 0, 0);
#pragma unroll
      for (int cb = 0; cb < 4; cb++) {
        const ushort* vb = &vbuf[sel][(cb * 16 + l15) * 64];
        union { short8 v; uint2 d2[2]; } vv;
        vv.d2[0] = *(const uint2*)(vb + vo[ks][0]);
        vv.d2[1] = *(const uint2*)(vb + vo[ks][1]);
#pragma unroll
        for (int qi = 0; qi < 4; qi++)
          o_acc[qi][cb] = __builtin_amdgcn_mfma_f32_16x16x32_bf16(vv.v, pbq[qi][ks].v, o_acc[qi][cb], 0, 0, 0);
      }
    }
    __builtin_amdgcn_s_setprio(0);
    __syncthreads();
  }

  // ---- epilogue: O^T / l -> o[B][S][H*64] (bf16, packed 8B stores) ----
#pragma unroll
  for (int qi = 0; qi < 4; qi++) {
    const float inv = 1.f / l_acc[qi][0];
    ushort* ob = o + ((size_t)b * S_ + q0 + w * 64 + qi * 16 + l15) * DM + h * HD + 4 * g;
#pragma unroll
    for (int cb = 0; cb < 4; cb++) {
      uint2 st;
      st.x = cvt_pk_bf16(o_acc[qi][cb][0] * inv, o_acc[qi][cb][1] * inv);
      st.y = cvt_pk_bf16(o_acc[qi][cb][2] * inv, o_acc[qi][cb][3] * inv);
      *(uint2*)(ob + cb * 16) = st;
    }
  }
}

// ---------------- launch ----------------
extern "C" void kernel_launch(void* const* d_in, const int* in_sizes, int n_in,
                              void* d_out, int out_size, void* d_ws, size_t ws_size,
                              hipStream_t stream) {
  const float* Q  = (const float*)d_in[0];
  const float* K  = (const float*)d_in[1];
  const float* V  = (const float*)d_in[2];
  const float* Wq = (const float*)d_in[3];
  const float* bq = (const float*)d_in[4];
  const float* Wk = (const float*)d_in[5];
  const float* bk = (const float*)d_in[6];
  const float* Wv = (const float*)d_in[7];
  const float* bv = (const float*)d_in[8];
  const float* Wo = (const float*)d_in[9];
  const float* bo = (const float*)d_in[10];
  float* out = (float*)d_out;
  ushort* ws = (ushort*)d_ws;

  const size_t WN = (size_t)1024 * 1024;       // weight elems
  const size_t PN = (size_t)B_ * S_ * DM;      // activation elems (8.39M)
  ushort* wqT = ws;
  ushort* wkT = ws + WN;
  ushort* wvT = ws + 2 * WN;
  ushort* woT = ws + 3 * WN;
  ushort* qws = ws + 4 * WN;
  ushort* kws = qws + PN;
  ushort* ows = kws + PN;
  ushort* vt  = (ushort*)d_out;  // V^T scratch in d_out (bf16 16.8MB < fp32 33.5MB); overwritten by final GEMM

  transposeW4<<<dim3(256, 4), 256, 0, stream>>>(Wq, Wk, Wv, Wo, ws);

  dim3 gg(64, 8);  // M/128 x N/128
  // Q pre-scaled by (1/8)*log2(e): attention scores land in the log2 domain
  gemm_bt<1, 1><<<gg, 256, 0, stream>>>(Q, wqT, bq, qws, 8192, 1024, 1024, 0.18033688f);
  gemm_bt<1, 1><<<gg, 256, 0, stream>>>(K, wkT, bk, kws, 8192, 1024, 1024, 1.0f);
  gemm_bt<1, 2><<<gg, 256, 0, stream>>>(V, wvT, bv, vt, 8192, 1024, 1024, 1.0f);

  attn<<<BH * 8, 256, 0, stream>>>(qws, kws, vt, ows);

  gemm_bt<0, 0><<<gg, 256, 0, stream>>>(ows, woT, bo, out, 8192, 1024, 1024, 1.0f);
}

// Round 8
// 190.900 us; speedup vs baseline: 1.1075x; 1.1075x over previous
//
#include <hip/hip_runtime.h>
#include <hip/hip_bf16.h>
#include <stdint.h>

// MHA: B=4, S=2048, D_MODEL=1024, H=16, hd=64.
// Interface: fp32 in / fp32 out. Internal compute: bf16 MFMA.

#define B_  4
#define S_  2048
#define DM  1024
#define H_  16
#define HD  64
#define BH  (B_ * H_)

typedef __attribute__((ext_vector_type(8))) short short8;
typedef __attribute__((ext_vector_type(4))) float f32x4;

union U8 { short8 v; ushort u[8]; };

__device__ __forceinline__ ushort f2bf(float f) {
  union { float f; uint32_t i; } x; x.f = f;
  uint32_t r = (x.i + 0x7FFFu + ((x.i >> 16) & 1u)) >> 16;
  return (ushort)r;
}

// packed f32x2 -> bf16x2 (RNE), gfx950 hw convert; no builtin exists (m240)
__device__ __forceinline__ uint32_t cvt_pk_bf16(float a, float b) {
  uint32_t r;
  asm("v_cvt_pk_bf16_f32 %0, %1, %2" : "=v"(r) : "v"(a), "v"(b));
  return r;
}

// raw 2^x (v_exp_f32 IS exp2)
__device__ __forceinline__ float exp2f_fast(float x) {
  float r;
  asm("v_exp_f32 %0, %1" : "=v"(r) : "v"(x));
  return r;
}

__device__ __forceinline__ void glds16(const ushort* g, ushort* l) {
  __builtin_amdgcn_global_load_lds(
      (const __attribute__((address_space(1))) void*)g,
      (__attribute__((address_space(3))) void*)l, 16, 0, 0);
}

#define MAX3(a, b, c) fmaxf(fmaxf((a), (b)), (c))

// ---------------- weight ingest: fp32 [1024][1024] -> bf16 transposed (4 fused) ----------------
__global__ __launch_bounds__(256) void transposeW4(
    const float* __restrict__ s0, const float* __restrict__ s1,
    const float* __restrict__ s2, const float* __restrict__ s3,
    ushort* __restrict__ dbase) {
  __shared__ __align__(16) ushort tile[64][72];
  const int t = threadIdx.x;
  const int bx = blockIdx.x & 15;   // src col block
  const int by = blockIdx.x >> 4;   // src row block
  const int wsel = blockIdx.y;
  const float* src = wsel == 0 ? s0 : (wsel == 1 ? s1 : (wsel == 2 ? s2 : s3));
  ushort* dst = dbase + (size_t)wsel * 1024 * 1024;
#pragma unroll
  for (int i = 0; i < 2; i++) {
    int e = (i * 256 + t) * 8;
    int r = e >> 6, c = e & 63;
    const float* sp = src + (size_t)(by * 64 + r) * 1024 + bx * 64 + c;
    float4 a = ((const float4*)sp)[0];
    float4 b = ((const float4*)sp)[1];
    tile[r][c + 0] = f2bf(a.x); tile[r][c + 1] = f2bf(a.y);
    tile[r][c + 2] = f2bf(a.z); tile[r][c + 3] = f2bf(a.w);
    tile[r][c + 4] = f2bf(b.x); tile[r][c + 5] = f2bf(b.y);
    tile[r][c + 6] = f2bf(b.z); tile[r][c + 7] = f2bf(b.w);
  }
  __syncthreads();
#pragma unroll
  for (int i = 0; i < 2; i++) {
    int e = (i * 256 + t) * 8;
    int r = e >> 6, c = e & 63;
    U8 st;
#pragma unroll
    for (int j = 0; j < 8; j++) st.u[j] = tile[c + j][r];
    *(short8*)(dst + (size_t)(bx * 64 + r) * 1024 + by * 64 + c) = st.v;
  }
}

// ---------------- fused QKV projection GEMM (z = 0/1/2 -> Q/K/V) ----------------
// R7 post-mortem: FUSED is the bench-level winner (~57us vs 72-81 unfused); R6's
// "L2 thrash" reading was a rocprof replay artifact — trust bench subtraction.
// A fp32 reg-staged + cvt_pk with next-iter prefetch (issued after the post-stage
// barrier so the vmcnt(0) drain excludes it; latency hides under ds_read+MFMA).
// z=0: Q -> bf16 head-split [B][H][S][64], oscale = log2(e)/8
// z=1: K -> bf16 head-split [B][H][S][64]
// z=2: V -> bf16 V^T [BH][64][S] with 8B-subchunk swizzle (phys = logical ^ (d&15))
__global__ __launch_bounds__(256, 2) void gemm_qkv(
    const float* __restrict__ Qa, const float* __restrict__ Ka, const float* __restrict__ Va,
    const ushort* __restrict__ WT,
    const float* __restrict__ bq, const float* __restrict__ bk, const float* __restrict__ bv,
    ushort* __restrict__ qws, ushort* __restrict__ kws, ushort* __restrict__ vt) {
  __shared__ __align__(16) ushort lA[128 * 32];
  __shared__ __align__(16) ushort lB[128 * 32];
  const int z = blockIdx.z;
  const float* Ap = z == 0 ? Qa : (z == 1 ? Ka : Va);
  const ushort* BT = WT + (size_t)z * 1024 * 1024;
  const float* bias = z == 0 ? bq : (z == 1 ? bk : bv);
  const float oscale = z == 0 ? 0.18033688f : 1.0f;  // (1/8)*log2(e) on Q
  const int t = threadIdx.x;
  const int lane = t & 63;
  const int w = t >> 6;
  const int wr = w >> 1, wc = w & 1;
  const int bm0 = blockIdx.x * 128;
  const int bn0 = blockIdx.y * 128;
  f32x4 acc[4][4] = {};

  const int arow = t >> 2;
  const int acol = (t & 3) * 8;
  const float* fA0 = Ap + (size_t)(bm0 + arow) * 1024 + acol;
  const float* fA1 = Ap + (size_t)(bm0 + 64 + arow) * 1024 + acol;
  const ushort* gB0 = BT + (size_t)(bn0 + arow) * 1024 + acol;
  const ushort* gB1 = BT + (size_t)(bn0 + 64 + arow) * 1024 + acol;

  float4 px0 = ((const float4*)fA0)[0];
  float4 px1 = ((const float4*)fA0)[1];
  float4 py0 = ((const float4*)fA1)[0];
  float4 py1 = ((const float4*)fA1)[1];

  for (int k0 = 0; k0 < 1024; k0 += 32) {
    if (k0) __syncthreads();
    union { short8 v; uint32_t u[4]; } s0, s1;
    s0.u[0] = cvt_pk_bf16(px0.x, px0.y); s0.u[1] = cvt_pk_bf16(px0.z, px0.w);
    s0.u[2] = cvt_pk_bf16(px1.x, px1.y); s0.u[3] = cvt_pk_bf16(px1.z, px1.w);
    s1.u[0] = cvt_pk_bf16(py0.x, py0.y); s1.u[1] = cvt_pk_bf16(py0.z, py0.w);
    s1.u[2] = cvt_pk_bf16(py1.x, py1.y); s1.u[3] = cvt_pk_bf16(py1.z, py1.w);
    *(short8*)&lA[t * 8] = s0.v;
    *(short8*)&lA[2048 + t * 8] = s1.v;
    glds16(gB0 + k0, &lB[t * 8]);
    glds16(gB1 + k0, &lB[2048 + t * 8]);
    __syncthreads();
    // prefetch next A slab AFTER the barrier (excluded from vmcnt(0) drain)
    if (k0 + 32 < 1024) {
      px0 = ((const float4*)(fA0 + k0 + 32))[0];
      px1 = ((const float4*)(fA0 + k0 + 32))[1];
      py0 = ((const float4*)(fA1 + k0 + 32))[0];
      py1 = ((const float4*)(fA1 + k0 + 32))[1];
    }
    short8 af[4], bf[4];
#pragma unroll
    for (int i = 0; i < 4; i++)
      af[i] = *(const short8*)&lA[(wr * 64 + i * 16 + (lane & 15)) * 32 + (lane >> 4) * 8];
#pragma unroll
    for (int j = 0; j < 4; j++)
      bf[j] = *(const short8*)&lB[(wc * 64 + j * 16 + (lane & 15)) * 32 + (lane >> 4) * 8];
#pragma unroll
    for (int i = 0; i < 4; i++)
#pragma unroll
      for (int j = 0; j < 4; j++)
        acc[i][j] = __builtin_amdgcn_mfma_f32_16x16x32_bf16(af[i], bf[j], acc[i][j], 0, 0, 0);
  }

  const int r0 = (lane >> 4) * 4;
#pragma unroll
  for (int j = 0; j < 4; j++) {
    const int col = bn0 + wc * 64 + j * 16 + (lane & 15);
    const float bc = bias[col];
#pragma unroll
    for (int i = 0; i < 4; i++) {
      const int row = bm0 + wr * 64 + i * 16 + r0;   // row % 4 == 0
      const int bb = row >> 11, s = row & 2047;
      const int hh = col >> 6, d = col & 63;
      if (z == 2) {
        uint32_t p01 = cvt_pk_bf16(acc[i][j][0] + bc, acc[i][j][1] + bc);
        uint32_t p23 = cvt_pk_bf16(acc[i][j][2] + bc, acc[i][j][3] + bc);
        ushort* vtb = vt + (((size_t)bb * H_ + hh) * HD + d) * (size_t)S_;
        const int sc = (s & 63) >> 2;
        *(uint2*)(vtb + (s & ~63) + ((sc ^ (d & 15)) << 2)) = (uint2){p01, p23};
      } else {
        ushort* dst = z == 0 ? qws : kws;
#pragma unroll
        for (int r = 0; r < 4; r++) {
          float val = (acc[i][j][r] + bc) * oscale;
          dst[(((size_t)bb * H_ + hh) * S_ + (s + r)) * HD + d] = f2bf(val);
        }
      }
    }
  }
}

// ---------------- output projection GEMM: fp32 C = A_bf16 * BT^T + bias ----------------
__global__ __launch_bounds__(256, 2) void gemm_out(
    const ushort* __restrict__ Ap, const ushort* __restrict__ BT,
    const float* __restrict__ bias, float* __restrict__ Cp) {
  __shared__ __align__(16) ushort lA[128 * 32];
  __shared__ __align__(16) ushort lB[128 * 32];
  const int t = threadIdx.x;
  const int lane = t & 63;
  const int w = t >> 6;
  const int wr = w >> 1, wc = w & 1;
  const int bm0 = blockIdx.x * 128;
  const int bn0 = blockIdx.y * 128;
  f32x4 acc[4][4] = {};

  const int arow = t >> 2;
  const int acol = (t & 3) * 8;
  const ushort* gA0 = Ap + (size_t)(bm0 + arow) * 1024 + acol;
  const ushort* gA1 = Ap + (size_t)(bm0 + 64 + arow) * 1024 + acol;
  const ushort* gB0 = BT + (size_t)(bn0 + arow) * 1024 + acol;
  const ushort* gB1 = BT + (size_t)(bn0 + 64 + arow) * 1024 + acol;

  for (int k0 = 0; k0 < 1024; k0 += 32) {
    if (k0) __syncthreads();
    glds16(gA0 + k0, &lA[t * 8]);
    glds16(gA1 + k0, &lA[2048 + t * 8]);
    glds16(gB0 + k0, &lB[t * 8]);
    glds16(gB1 + k0, &lB[2048 + t * 8]);
    __syncthreads();
    short8 af[4], bf[4];
#pragma unroll
    for (int i = 0; i < 4; i++)
      af[i] = *(const short8*)&lA[(wr * 64 + i * 16 + (lane & 15)) * 32 + (lane >> 4) * 8];
#pragma unroll
    for (int j = 0; j < 4; j++)
      bf[j] = *(const short8*)&lB[(wc * 64 + j * 16 + (lane & 15)) * 32 + (lane >> 4) * 8];
#pragma unroll
    for (int i = 0; i < 4; i++)
#pragma unroll
      for (int j = 0; j < 4; j++)
        acc[i][j] = __builtin_amdgcn_mfma_f32_16x16x32_bf16(af[i], bf[j], acc[i][j], 0, 0, 0);
  }

  const int r0 = (lane >> 4) * 4;
#pragma unroll
  for (int j = 0; j < 4; j++) {
    const int col = bn0 + wc * 64 + j * 16 + (lane & 15);
    const float bc = bias[col];
#pragma unroll
    for (int i = 0; i < 4; i++) {
      const int row = bm0 + wr * 64 + i * 16 + r0;
#pragma unroll
      for (int r = 0; r < 4; r++)
        Cp[(size_t)(row + r) * 1024 + col] = acc[i][j][r] + bc;
    }
  }
}

// ---------------- flash attention (swapped-QK^T, in-register P, KVBLK=128) ----------------
// R7 post-mortem: wall 106us vs VALU-busy 49 + MFMA 32 -> ~57us dead time from the
// per-tile barrier + vmcnt(0) drain (32 rounds). Fix: KVBLK=128 staged per round,
// processed as TWO sequential 64-wide halves (identical math/registers per half,
// numerically identical tile sequence) -> 16 barrier rounds instead of 32, and each
// prefetch gets 2x compute to land under. LDS 64KB (2 blocks/CU, grid-limited).
// q,k: bf16 [BH][S][64] (q pre-scaled by log2(e)/8), vt: bf16 [BH][64][S] 8B-swizzled,
// o: bf16 [B][S][1024]
__global__ __launch_bounds__(256, 2) void attn(
    const ushort* __restrict__ q, const ushort* __restrict__ k,
    const ushort* __restrict__ vt, ushort* __restrict__ o) {
  __shared__ __align__(16) ushort kbuf[2][8192];   // 128 kv-rows x 64 d
  __shared__ __align__(16) ushort vbuf[2][8192];   // 64 d-rows x 128 s
  const int t = threadIdx.x;
  const int lane = t & 63;
  const int w = t >> 6;
  // XCD-bijective swizzle: 512 blocks, 8 q-tiles/head -> each XCD owns 8 whole heads
  const int L = ((blockIdx.x & 7) << 6) + (blockIdx.x >> 3);
  const int bh = L >> 3;
  const int q0 = (L & 7) * 256;
  const int b = bh >> 4, h = bh & 15;
  const int l15 = lane & 15;
  const int g = lane >> 4;

  const ushort* kbase  = k  + (size_t)bh * S_ * HD;
  const ushort* vtbase = vt + (size_t)bh * HD * S_;

  // Q fragments: 64 rows per wave (4 x 16), hd=64 in two x-slabs (MFMA B operand)
  short8 qf[4][2];
#pragma unroll
  for (int qi = 0; qi < 4; qi++) {
    const ushort* qp = q + ((size_t)bh * S_ + q0 + w * 64 + qi * 16 + l15) * HD + g * 8;
    qf[qi][0] = *(const short8*)qp;
    qf[qi][1] = *(const short8*)(qp + 32);
  }

  // ones A-fragment for l accumulation (bf16 1.0 = 0x3F80)
  short8 onesf;
#pragma unroll
  for (int j = 0; j < 8; j++) onesf[j] = (short)0x3F80;

  float m_r[4] = {-1e30f, -1e30f, -1e30f, -1e30f};
  f32x4 l_acc[4];
  f32x4 o_acc[4][4];
#pragma unroll
  for (int qi = 0; qi < 4; qi++) {
    l_acc[qi] = (f32x4){0.f, 0.f, 0.f, 0.f};
#pragma unroll
    for (int cb = 0; cb < 4; cb++) o_acc[qi][cb] = (f32x4){0.f, 0.f, 0.f, 0.f};
  }

  // V-read sub-chunk offsets (ushort units), loop/cb-invariant: (8ks+g+{0,4}) ^ l15
  int vo[2][2];
#pragma unroll
  for (int ks = 0; ks < 2; ks++) {
    vo[ks][0] = ((8 * ks + g) ^ l15) << 2;
    vo[ks][1] = ((8 * ks + 4 + g) ^ l15) << 2;
  }

  // stage one 128-kv tile: K [128][64] with XOR-swizzled source (16B chunks),
  // V [64][128] linear (8B swizzle pre-baked in vt per 64-col block)
  auto STAGE = [&](int sel_, int kv0) {
#pragma unroll
    for (int i = 0; i < 4; i++) {
      int c = i * 256 + t;              // chunk 0..1023
      int krow = c >> 3;                // 0..127
      int kcc = (c & 7) ^ (krow & 7);
      glds16(kbase + (size_t)(kv0 + krow) * HD + kcc * 8, &kbuf[sel_][c * 8]);
      int d = c >> 4;                   // 0..63
      int voff = ((c >> 3) & 1) * 64 + (c & 7) * 8;
      glds16(vtbase + (size_t)d * S_ + kv0 + voff, &vbuf[sel_][c * 8]);
    }
  };

  STAGE(0, 0);
  __syncthreads();

  int sel = 0;
  for (int kv0 = 0; kv0 < S_; kv0 += 128, sel ^= 1) {
    if (kv0 + 128 < S_) STAGE(sel ^ 1, kv0 + 128);

#pragma unroll
    for (int hb = 0; hb < 2; hb++) {
      // ---- S^T = K (Q*log2e/8)^T for this 64-wide half ----
      f32x4 sc[4][4];
#pragma unroll
      for (int qi = 0; qi < 4; qi++)
#pragma unroll
        for (int cb = 0; cb < 4; cb++) sc[qi][cb] = (f32x4){0.f, 0.f, 0.f, 0.f};
      __builtin_amdgcn_s_setprio(1);
#pragma unroll
      for (int cb = 0; cb < 4; cb++) {
        const int row = hb * 64 + cb * 16 + l15;
        const int r7 = row & 7;
        short8 kf0 = *(const short8*)&kbuf[sel][(row * 8 + (g ^ r7)) * 8];
        short8 kf1 = *(const short8*)&kbuf[sel][(row * 8 + ((4 + g) ^ r7)) * 8];
#pragma unroll
        for (int qi = 0; qi < 4; qi++) {
          sc[qi][cb] = __builtin_amdgcn_mfma_f32_16x16x32_bf16(kf0, qf[qi][0], sc[qi][cb], 0, 0, 0);
          sc[qi][cb] = __builtin_amdgcn_mfma_f32_16x16x32_bf16(kf1, qf[qi][1], sc[qi][cb], 0, 0, 0);
        }
      }
      __builtin_amdgcn_s_setprio(0);

      // ---- softmax per qi (optimistic exp; shfl max off critical path) ----
      union PB { short8 v; uint32_t u[4]; } pbq[4][2];
#pragma unroll
      for (int qi = 0; qi < 4; qi++) {
        const float m = m_r[qi];
#pragma unroll
        for (int cb = 0; cb < 4; cb++) {
          float p0 = exp2f_fast(sc[qi][cb][0] - m);
          float p1 = exp2f_fast(sc[qi][cb][1] - m);
          float p2 = exp2f_fast(sc[qi][cb][2] - m);
          float p3 = exp2f_fast(sc[qi][cb][3] - m);
          pbq[qi][cb >> 1].u[(cb & 1) * 2 + 0] = cvt_pk_bf16(p0, p1);
          pbq[qi][cb >> 1].u[(cb & 1) * 2 + 1] = cvt_pk_bf16(p2, p3);
        }
        float z0 = MAX3(sc[qi][0][0], sc[qi][0][1], sc[qi][0][2]);
        float z1 = MAX3(sc[qi][0][3], sc[qi][1][0], sc[qi][1][1]);
        float z2 = MAX3(sc[qi][1][2], sc[qi][1][3], sc[qi][2][0]);
        float z3 = MAX3(sc[qi][2][1], sc[qi][2][2], sc[qi][2][3]);
        float z4 = MAX3(sc[qi][3][0], sc[qi][3][1], sc[qi][3][2]);
        float mx = MAX3(MAX3(z0, z1, z2), fmaxf(z3, z4), sc[qi][3][3]);
        mx = fmaxf(mx, __shfl_xor(mx, 16));
        mx = fmaxf(mx, __shfl_xor(mx, 32));

        const float THR = 11.5415603f;  // 8 * log2(e)
        if (!__all(mx <= m + THR)) {
          float mn = fmaxf(m, mx);
          float fct = exp2f_fast(m - mn);
          m_r[qi] = mn;
          l_acc[qi] *= fct;
#pragma unroll
          for (int cb = 0; cb < 4; cb++)
#pragma unroll
            for (int r = 0; r < 4; r++) o_acc[qi][cb][r] *= fct;
#pragma unroll
          for (int cb = 0; cb < 4; cb++) {
            float p0 = exp2f_fast(sc[qi][cb][0] - mn);
            float p1 = exp2f_fast(sc[qi][cb][1] - mn);
            float p2 = exp2f_fast(sc[qi][cb][2] - mn);
            float p3 = exp2f_fast(sc[qi][cb][3] - mn);
            pbq[qi][cb >> 1].u[(cb & 1) * 2 + 0] = cvt_pk_bf16(p0, p1);
            pbq[qi][cb >> 1].u[(cb & 1) * 2 + 1] = cvt_pk_bf16(p2, p3);
          }
        }
      }

      // ---- O^T += V^T P^T, l += 1.P ; vv loaded once per (ks,cb), reused by 4 qi ----
      __builtin_amdgcn_s_setprio(1);
#pragma unroll
      for (int ks = 0; ks < 2; ks++) {
#pragma unroll
        for (int qi = 0; qi < 4; qi++)
          l_acc[qi] = __builtin_amdgcn_mfma_f32_16x16x32_bf16(onesf, pbq[qi][ks].v, l_acc[qi], 0, 0, 0);
#pragma unroll
        for (int cb = 0; cb < 4; cb++) {
          const ushort* vb = &vbuf[sel][(cb * 16 + l15) * 128 + hb * 64];
          union { short8 v; uint2 d2[2]; } vv;
          vv.d2[0] = *(const uint2*)(vb + vo[ks][0]);
          vv.d2[1] = *(const uint2*)(vb + vo[ks][1]);
#pragma unroll
          for (int qi = 0; qi < 4; qi++)
            o_acc[qi][cb] = __builtin_amdgcn_mfma_f32_16x16x32_bf16(vv.v, pbq[qi][ks].v, o_acc[qi][cb], 0, 0, 0);
        }
      }
      __builtin_amdgcn_s_setprio(0);
    }
    __syncthreads();
  }

  // ---- epilogue: O^T / l -> o[B][S][H*64] (bf16, packed 8B stores) ----
#pragma unroll
  for (int qi = 0; qi < 4; qi++) {
    const float inv = 1.f / l_acc[qi][0];
    ushort* ob = o + ((size_t)b * S_ + q0 + w * 64 + qi * 16 + l15) * DM + h * HD + 4 * g;
#pragma unroll
    for (int cb = 0; cb < 4; cb++) {
      uint2 st;
      st.x = cvt_pk_bf16(o_acc[qi][cb][0] * inv, o_acc[qi][cb][1] * inv);
      st.y = cvt_pk_bf16(o_acc[qi][cb][2] * inv, o_acc[qi][cb][3] * inv);
      *(uint2*)(ob + cb * 16) = st;
    }
  }
}

// ---------------- launch ----------------
extern "C" void kernel_launch(void* const* d_in, const int* in_sizes, int n_in,
                              void* d_out, int out_size, void* d_ws, size_t ws_size,
                              hipStream_t stream) {
  const float* Q  = (const float*)d_in[0];
  const float* K  = (const float*)d_in[1];
  const float* V  = (const float*)d_in[2];
  const float* Wq = (const float*)d_in[3];
  const float* bq = (const float*)d_in[4];
  const float* Wk = (const float*)d_in[5];
  const float* bk = (const float*)d_in[6];
  const float* Wv = (const float*)d_in[7];
  const float* bv = (const float*)d_in[8];
  const float* Wo = (const float*)d_in[9];
  const float* bo = (const float*)d_in[10];
  float* out = (float*)d_out;
  ushort* ws = (ushort*)d_ws;

  const size_t WN = (size_t)1024 * 1024;       // weight elems
  const size_t PN = (size_t)B_ * S_ * DM;      // activation elems (8.39M)
  ushort* wT  = ws;                             // wq/wk/wv/wo transposed, contiguous
  ushort* woT = ws + 3 * WN;
  ushort* qws = ws + 4 * WN;
  ushort* kws = qws + PN;
  ushort* ows = kws + PN;
  ushort* vt  = (ushort*)d_out;  // V^T scratch in d_out (bf16 16.8MB < fp32 33.5MB); overwritten by final GEMM

  transposeW4<<<dim3(256, 4), 256, 0, stream>>>(Wq, Wk, Wv, Wo, wT);

  // fused Q/K/V projections (bench-level winner per R7 post-mortem)
  gemm_qkv<<<dim3(64, 8, 3), 256, 0, stream>>>(Q, K, V, wT, bq, bk, bv, qws, kws, vt);

  attn<<<BH * 8, 256, 0, stream>>>(qws, kws, vt, ows);

  gemm_out<<<dim3(64, 8), 256, 0, stream>>>(ows, woT, bo, out);
}

// Round 9
// 190.330 us; speedup vs baseline: 1.1108x; 1.0030x over previous
//
#include <hip/hip_runtime.h>
#include <hip/hip_bf16.h>
#include <stdint.h>

// MHA: B=4, S=2048, D_MODEL=1024, H=16, hd=64.
// Interface: fp32 in / fp32 out. Internal compute: bf16 MFMA.

#define B_  4
#define S_  2048
#define DM  1024
#define H_  16
#define HD  64
#define BH  (B_ * H_)

typedef __attribute__((ext_vector_type(8))) short short8;
typedef __attribute__((ext_vector_type(4))) float f32x4;

union U8 { short8 v; ushort u[8]; };

__device__ __forceinline__ ushort f2bf(float f) {
  union { float f; uint32_t i; } x; x.f = f;
  uint32_t r = (x.i + 0x7FFFu + ((x.i >> 16) & 1u)) >> 16;
  return (ushort)r;
}

// packed f32x2 -> bf16x2 (RNE), gfx950 hw convert; no builtin exists (m240)
__device__ __forceinline__ uint32_t cvt_pk_bf16(float a, float b) {
  uint32_t r;
  asm("v_cvt_pk_bf16_f32 %0, %1, %2" : "=v"(r) : "v"(a), "v"(b));
  return r;
}

// raw 2^x (v_exp_f32 IS exp2)
__device__ __forceinline__ float exp2f_fast(float x) {
  float r;
  asm("v_exp_f32 %0, %1" : "=v"(r) : "v"(x));
  return r;
}

__device__ __forceinline__ void glds16(const ushort* g, ushort* l) {
  __builtin_amdgcn_global_load_lds(
      (const __attribute__((address_space(1))) void*)g,
      (__attribute__((address_space(3))) void*)l, 16, 0, 0);
}

#define MAX3(a, b, c) fmaxf(fmaxf((a), (b)), (c))

// ---------------- weight ingest: fp32 [1024][1024] -> bf16 transposed (4 fused) ----------------
__global__ __launch_bounds__(256) void transposeW4(
    const float* __restrict__ s0, const float* __restrict__ s1,
    const float* __restrict__ s2, const float* __restrict__ s3,
    ushort* __restrict__ dbase) {
  __shared__ __align__(16) ushort tile[64][72];
  const int t = threadIdx.x;
  const int bx = blockIdx.x & 15;   // src col block
  const int by = blockIdx.x >> 4;   // src row block
  const int wsel = blockIdx.y;
  const float* src = wsel == 0 ? s0 : (wsel == 1 ? s1 : (wsel == 2 ? s2 : s3));
  ushort* dst = dbase + (size_t)wsel * 1024 * 1024;
#pragma unroll
  for (int i = 0; i < 2; i++) {
    int e = (i * 256 + t) * 8;
    int r = e >> 6, c = e & 63;
    const float* sp = src + (size_t)(by * 64 + r) * 1024 + bx * 64 + c;
    float4 a = ((const float4*)sp)[0];
    float4 b = ((const float4*)sp)[1];
    tile[r][c + 0] = f2bf(a.x); tile[r][c + 1] = f2bf(a.y);
    tile[r][c + 2] = f2bf(a.z); tile[r][c + 3] = f2bf(a.w);
    tile[r][c + 4] = f2bf(b.x); tile[r][c + 5] = f2bf(b.y);
    tile[r][c + 6] = f2bf(b.z); tile[r][c + 7] = f2bf(b.w);
  }
  __syncthreads();
#pragma unroll
  for (int i = 0; i < 2; i++) {
    int e = (i * 256 + t) * 8;
    int r = e >> 6, c = e & 63;
    U8 st;
#pragma unroll
    for (int j = 0; j < 8; j++) st.u[j] = tile[c + j][r];
    *(short8*)(dst + (size_t)(bx * 64 + r) * 1024 + by * 64 + c) = st.v;
  }
}

// GEMM LDS tile swizzle (R8 post-mortem): linear [row][32] bf16 tiles read as
// row*32 + g*8 are an 8-WAY bank conflict per 16-lane phase (64B row stride aliases
// mod the 128B bank stripe; SQ_LDS_BANK_CONFLICT = 6.29M in gemm_qkv). Fix:
// phys_chunk = logical_chunk ^ ((row>>1)&3). Reads become 2 lanes/bank (free).
// A-side (ds_write): write to the swizzled slot. B-side (glds16, dest must stay
// linear): pre-swizzle the GLOBAL source column (bijective within each row).
//   stage source/slot key for thread t: (t&3) ^ ((t>>3)&3)
//   read chunk offset for lane:         (lane>>4) ^ ((lane>>1)&3)

// ---------------- fused QKV projection GEMM (z = 0/1/2 -> Q/K/V) ----------------
// FUSED is the bench-level winner (R7 post-mortem; trust bench subtraction).
// A fp32 reg-staged + cvt_pk with next-iter prefetch after the post-stage barrier.
// z=0: Q -> bf16 head-split [B][H][S][64], oscale = log2(e)/8
// z=1: K -> bf16 head-split [B][H][S][64]
// z=2: V -> bf16 V^T [BH][64][S] with 8B-subchunk swizzle (phys = logical ^ (d&15))
__global__ __launch_bounds__(256, 2) void gemm_qkv(
    const float* __restrict__ Qa, const float* __restrict__ Ka, const float* __restrict__ Va,
    const ushort* __restrict__ WT,
    const float* __restrict__ bq, const float* __restrict__ bk, const float* __restrict__ bv,
    ushort* __restrict__ qws, ushort* __restrict__ kws, ushort* __restrict__ vt) {
  __shared__ __align__(16) ushort lA[128 * 32];
  __shared__ __align__(16) ushort lB[128 * 32];
  const int z = blockIdx.z;
  const float* Ap = z == 0 ? Qa : (z == 1 ? Ka : Va);
  const ushort* BT = WT + (size_t)z * 1024 * 1024;
  const float* bias = z == 0 ? bq : (z == 1 ? bk : bv);
  const float oscale = z == 0 ? 0.18033688f : 1.0f;  // (1/8)*log2(e) on Q
  const int t = threadIdx.x;
  const int lane = t & 63;
  const int w = t >> 6;
  const int wr = w >> 1, wc = w & 1;
  const int bm0 = blockIdx.x * 128;
  const int bn0 = blockIdx.y * 128;
  f32x4 acc[4][4] = {};

  const int arow = t >> 2;
  const int acol = (t & 3) * 8;                       // A fp32 source (unswizzled; reg-staged)
  const int swz  = ((t & 3) ^ ((t >> 3) & 3)) * 8;    // swizzled chunk (stage key)
  const int rdo  = (((lane >> 4) ^ ((lane >> 1) & 3))) * 8;  // read chunk offset
  const float* fA0 = Ap + (size_t)(bm0 + arow) * 1024 + acol;
  const float* fA1 = Ap + (size_t)(bm0 + 64 + arow) * 1024 + acol;
  const ushort* gB0 = BT + (size_t)(bn0 + arow) * 1024 + swz;       // pre-swizzled source col
  const ushort* gB1 = BT + (size_t)(bn0 + 64 + arow) * 1024 + swz;
  ushort* lAs0 = &lA[(t >> 2) * 32 + swz];            // swizzled ds_write dests
  ushort* lAs1 = &lA[2048 + (t >> 2) * 32 + swz];

  float4 px0 = ((const float4*)fA0)[0];
  float4 px1 = ((const float4*)fA0)[1];
  float4 py0 = ((const float4*)fA1)[0];
  float4 py1 = ((const float4*)fA1)[1];

  for (int k0 = 0; k0 < 1024; k0 += 32) {
    if (k0) __syncthreads();
    union { short8 v; uint32_t u[4]; } s0, s1;
    s0.u[0] = cvt_pk_bf16(px0.x, px0.y); s0.u[1] = cvt_pk_bf16(px0.z, px0.w);
    s0.u[2] = cvt_pk_bf16(px1.x, px1.y); s0.u[3] = cvt_pk_bf16(px1.z, px1.w);
    s1.u[0] = cvt_pk_bf16(py0.x, py0.y); s1.u[1] = cvt_pk_bf16(py0.z, py0.w);
    s1.u[2] = cvt_pk_bf16(py1.x, py1.y); s1.u[3] = cvt_pk_bf16(py1.z, py1.w);
    *(short8*)lAs0 = s0.v;
    *(short8*)lAs1 = s1.v;
    glds16(gB0 + k0, &lB[t * 8]);
    glds16(gB1 + k0, &lB[2048 + t * 8]);
    __syncthreads();
    // prefetch next A slab AFTER the barrier (excluded from vmcnt(0) drain)
    if (k0 + 32 < 1024) {
      px0 = ((const float4*)(fA0 + k0 + 32))[0];
      px1 = ((const float4*)(fA0 + k0 + 32))[1];
      py0 = ((const float4*)(fA1 + k0 + 32))[0];
      py1 = ((const float4*)(fA1 + k0 + 32))[1];
    }
    short8 af[4], bf[4];
#pragma unroll
    for (int i = 0; i < 4; i++)
      af[i] = *(const short8*)&lA[(wr * 64 + i * 16 + (lane & 15)) * 32 + rdo];
#pragma unroll
    for (int j = 0; j < 4; j++)
      bf[j] = *(const short8*)&lB[(wc * 64 + j * 16 + (lane & 15)) * 32 + rdo];
#pragma unroll
    for (int i = 0; i < 4; i++)
#pragma unroll
      for (int j = 0; j < 4; j++)
        acc[i][j] = __builtin_amdgcn_mfma_f32_16x16x32_bf16(af[i], bf[j], acc[i][j], 0, 0, 0);
  }

  const int r0 = (lane >> 4) * 4;
#pragma unroll
  for (int j = 0; j < 4; j++) {
    const int col = bn0 + wc * 64 + j * 16 + (lane & 15);
    const float bc = bias[col];
#pragma unroll
    for (int i = 0; i < 4; i++) {
      const int row = bm0 + wr * 64 + i * 16 + r0;   // row % 4 == 0
      const int bb = row >> 11, s = row & 2047;
      const int hh = col >> 6, d = col & 63;
      if (z == 2) {
        uint32_t p01 = cvt_pk_bf16(acc[i][j][0] + bc, acc[i][j][1] + bc);
        uint32_t p23 = cvt_pk_bf16(acc[i][j][2] + bc, acc[i][j][3] + bc);
        ushort* vtb = vt + (((size_t)bb * H_ + hh) * HD + d) * (size_t)S_;
        const int sc = (s & 63) >> 2;
        *(uint2*)(vtb + (s & ~63) + ((sc ^ (d & 15)) << 2)) = (uint2){p01, p23};
      } else {
        ushort* dst = z == 0 ? qws : kws;
#pragma unroll
        for (int r = 0; r < 4; r++) {
          float val = (acc[i][j][r] + bc) * oscale;
          dst[(((size_t)bb * H_ + hh) * S_ + (s + r)) * HD + d] = f2bf(val);
        }
      }
    }
  }
}

// ---------------- output projection GEMM: fp32 C = A_bf16 * BT^T + bias ----------------
__global__ __launch_bounds__(256, 2) void gemm_out(
    const ushort* __restrict__ Ap, const ushort* __restrict__ BT,
    const float* __restrict__ bias, float* __restrict__ Cp) {
  __shared__ __align__(16) ushort lA[128 * 32];
  __shared__ __align__(16) ushort lB[128 * 32];
  const int t = threadIdx.x;
  const int lane = t & 63;
  const int w = t >> 6;
  const int wr = w >> 1, wc = w & 1;
  const int bm0 = blockIdx.x * 128;
  const int bn0 = blockIdx.y * 128;
  f32x4 acc[4][4] = {};

  const int arow = t >> 2;
  const int swz  = ((t & 3) ^ ((t >> 3) & 3)) * 8;    // pre-swizzled source col (see swizzle note)
  const int rdo  = (((lane >> 4) ^ ((lane >> 1) & 3))) * 8;
  const ushort* gA0 = Ap + (size_t)(bm0 + arow) * 1024 + swz;
  const ushort* gA1 = Ap + (size_t)(bm0 + 64 + arow) * 1024 + swz;
  const ushort* gB0 = BT + (size_t)(bn0 + arow) * 1024 + swz;
  const ushort* gB1 = BT + (size_t)(bn0 + 64 + arow) * 1024 + swz;

  for (int k0 = 0; k0 < 1024; k0 += 32) {
    if (k0) __syncthreads();
    glds16(gA0 + k0, &lA[t * 8]);
    glds16(gA1 + k0, &lA[2048 + t * 8]);
    glds16(gB0 + k0, &lB[t * 8]);
    glds16(gB1 + k0, &lB[2048 + t * 8]);
    __syncthreads();
    short8 af[4], bf[4];
#pragma unroll
    for (int i = 0; i < 4; i++)
      af[i] = *(const short8*)&lA[(wr * 64 + i * 16 + (lane & 15)) * 32 + rdo];
#pragma unroll
    for (int j = 0; j < 4; j++)
      bf[j] = *(const short8*)&lB[(wc * 64 + j * 16 + (lane & 15)) * 32 + rdo];
#pragma unroll
    for (int i = 0; i < 4; i++)
#pragma unroll
      for (int j = 0; j < 4; j++)
        acc[i][j] = __builtin_amdgcn_mfma_f32_16x16x32_bf16(af[i], bf[j], acc[i][j], 0, 0, 0);
  }

  const int r0 = (lane >> 4) * 4;
#pragma unroll
  for (int j = 0; j < 4; j++) {
    const int col = bn0 + wc * 64 + j * 16 + (lane & 15);
    const float bc = bias[col];
#pragma unroll
    for (int i = 0; i < 4; i++) {
      const int row = bm0 + wr * 64 + i * 16 + r0;
#pragma unroll
      for (int r = 0; r < 4; r++)
        Cp[(size_t)(row + r) * 1024 + col] = acc[i][j][r] + bc;
    }
  }
}

// ---------------- flash attention (swapped-QK^T, in-register P, KVBLK=128) ----------------
// R8 post-mortem: attn pinned ~101-113us across occupancy/LDS/barrier variants;
// MfmaUtil+VALUBusy sum to ~77% (pipes NOT overlapping across the 2 co-resident
// waves/SIMD). Suspect: s_setprio(1) around MFMA clusters starves the neighbor
// wave's prio-0 softmax VALU (guide T5: structure-conditional, hurts GEMM-like
// lockstep). THIS ROUND: setprio REMOVED (A/B experiment; restore if it regresses).
// q,k: bf16 [BH][S][64] (q pre-scaled by log2(e)/8), vt: bf16 [BH][64][S] 8B-swizzled,
// o: bf16 [B][S][1024]
__global__ __launch_bounds__(256, 2) void attn(
    const ushort* __restrict__ q, const ushort* __restrict__ k,
    const ushort* __restrict__ vt, ushort* __restrict__ o) {
  __shared__ __align__(16) ushort kbuf[2][8192];   // 128 kv-rows x 64 d
  __shared__ __align__(16) ushort vbuf[2][8192];   // 64 d-rows x 128 s
  const int t = threadIdx.x;
  const int lane = t & 63;
  const int w = t >> 6;
  // XCD-bijective swizzle: 512 blocks, 8 q-tiles/head -> each XCD owns 8 whole heads
  const int L = ((blockIdx.x & 7) << 6) + (blockIdx.x >> 3);
  const int bh = L >> 3;
  const int q0 = (L & 7) * 256;
  const int b = bh >> 4, h = bh & 15;
  const int l15 = lane & 15;
  const int g = lane >> 4;

  const ushort* kbase  = k  + (size_t)bh * S_ * HD;
  const ushort* vtbase = vt + (size_t)bh * HD * S_;

  // Q fragments: 64 rows per wave (4 x 16), hd=64 in two x-slabs (MFMA B operand)
  short8 qf[4][2];
#pragma unroll
  for (int qi = 0; qi < 4; qi++) {
    const ushort* qp = q + ((size_t)bh * S_ + q0 + w * 64 + qi * 16 + l15) * HD + g * 8;
    qf[qi][0] = *(const short8*)qp;
    qf[qi][1] = *(const short8*)(qp + 32);
  }

  // ones A-fragment for l accumulation (bf16 1.0 = 0x3F80)
  short8 onesf;
#pragma unroll
  for (int j = 0; j < 8; j++) onesf[j] = (short)0x3F80;

  float m_r[4] = {-1e30f, -1e30f, -1e30f, -1e30f};
  f32x4 l_acc[4];
  f32x4 o_acc[4][4];
#pragma unroll
  for (int qi = 0; qi < 4; qi++) {
    l_acc[qi] = (f32x4){0.f, 0.f, 0.f, 0.f};
#pragma unroll
    for (int cb = 0; cb < 4; cb++) o_acc[qi][cb] = (f32x4){0.f, 0.f, 0.f, 0.f};
  }

  // V-read sub-chunk offsets (ushort units), loop/cb-invariant: (8ks+g+{0,4}) ^ l15
  int vo[2][2];
#pragma unroll
  for (int ks = 0; ks < 2; ks++) {
    vo[ks][0] = ((8 * ks + g) ^ l15) << 2;
    vo[ks][1] = ((8 * ks + 4 + g) ^ l15) << 2;
  }

  // stage one 128-kv tile: K [128][64] with XOR-swizzled source (16B chunks),
  // V [64][128] linear (8B swizzle pre-baked in vt per 64-col block)
  auto STAGE = [&](int sel_, int kv0) {
#pragma unroll
    for (int i = 0; i < 4; i++) {
      int c = i * 256 + t;              // chunk 0..1023
      int krow = c >> 3;                // 0..127
      int kcc = (c & 7) ^ (krow & 7);
      glds16(kbase + (size_t)(kv0 + krow) * HD + kcc * 8, &kbuf[sel_][c * 8]);
      int d = c >> 4;                   // 0..63
      int voff = ((c >> 3) & 1) * 64 + (c & 7) * 8;
      glds16(vtbase + (size_t)d * S_ + kv0 + voff, &vbuf[sel_][c * 8]);
    }
  };

  STAGE(0, 0);
  __syncthreads();

  int sel = 0;
  for (int kv0 = 0; kv0 < S_; kv0 += 128, sel ^= 1) {
    if (kv0 + 128 < S_) STAGE(sel ^ 1, kv0 + 128);

#pragma unroll
    for (int hb = 0; hb < 2; hb++) {
      // ---- S^T = K (Q*log2e/8)^T for this 64-wide half ----
      f32x4 sc[4][4];
#pragma unroll
      for (int qi = 0; qi < 4; qi++)
#pragma unroll
        for (int cb = 0; cb < 4; cb++) sc[qi][cb] = (f32x4){0.f, 0.f, 0.f, 0.f};
#pragma unroll
      for (int cb = 0; cb < 4; cb++) {
        const int row = hb * 64 + cb * 16 + l15;
        const int r7 = row & 7;
        short8 kf0 = *(const short8*)&kbuf[sel][(row * 8 + (g ^ r7)) * 8];
        short8 kf1 = *(const short8*)&kbuf[sel][(row * 8 + ((4 + g) ^ r7)) * 8];
#pragma unroll
        for (int qi = 0; qi < 4; qi++) {
          sc[qi][cb] = __builtin_amdgcn_mfma_f32_16x16x32_bf16(kf0, qf[qi][0], sc[qi][cb], 0, 0, 0);
          sc[qi][cb] = __builtin_amdgcn_mfma_f32_16x16x32_bf16(kf1, qf[qi][1], sc[qi][cb], 0, 0, 0);
        }
      }

      // ---- softmax per qi (optimistic exp; shfl max off critical path) ----
      union PB { short8 v; uint32_t u[4]; } pbq[4][2];
#pragma unroll
      for (int qi = 0; qi < 4; qi++) {
        const float m = m_r[qi];
#pragma unroll
        for (int cb = 0; cb < 4; cb++) {
          float p0 = exp2f_fast(sc[qi][cb][0] - m);
          float p1 = exp2f_fast(sc[qi][cb][1] - m);
          float p2 = exp2f_fast(sc[qi][cb][2] - m);
          float p3 = exp2f_fast(sc[qi][cb][3] - m);
          pbq[qi][cb >> 1].u[(cb & 1) * 2 + 0] = cvt_pk_bf16(p0, p1);
          pbq[qi][cb >> 1].u[(cb & 1) * 2 + 1] = cvt_pk_bf16(p2, p3);
        }
        float z0 = MAX3(sc[qi][0][0], sc[qi][0][1], sc[qi][0][2]);
        float z1 = MAX3(sc[qi][0][3], sc[qi][1][0], sc[qi][1][1]);
        float z2 = MAX3(sc[qi][1][2], sc[qi][1][3], sc[qi][2][0]);
        float z3 = MAX3(sc[qi][2][1], sc[qi][2][2], sc[qi][2][3]);
        float z4 = MAX3(sc[qi][3][0], sc[qi][3][1], sc[qi][3][2]);
        float mx = MAX3(MAX3(z0, z1, z2), fmaxf(z3, z4), sc[qi][3][3]);
        mx = fmaxf(mx, __shfl_xor(mx, 16));
        mx = fmaxf(mx, __shfl_xor(mx, 32));

        const float THR = 11.5415603f;  // 8 * log2(e)
        if (!__all(mx <= m + THR)) {
          float mn = fmaxf(m, mx);
          float fct = exp2f_fast(m - mn);
          m_r[qi] = mn;
          l_acc[qi] *= fct;
#pragma unroll
          for (int cb = 0; cb < 4; cb++)
#pragma unroll
            for (int r = 0; r < 4; r++) o_acc[qi][cb][r] *= fct;
#pragma unroll
          for (int cb = 0; cb < 4; cb++) {
            float p0 = exp2f_fast(sc[qi][cb][0] - mn);
            float p1 = exp2f_fast(sc[qi][cb][1] - mn);
            float p2 = exp2f_fast(sc[qi][cb][2] - mn);
            float p3 = exp2f_fast(sc[qi][cb][3] - mn);
            pbq[qi][cb >> 1].u[(cb & 1) * 2 + 0] = cvt_pk_bf16(p0, p1);
            pbq[qi][cb >> 1].u[(cb & 1) * 2 + 1] = cvt_pk_bf16(p2, p3);
          }
        }
      }

      // ---- O^T += V^T P^T, l += 1.P ; vv loaded once per (ks,cb), reused by 4 qi ----
#pragma unroll
      for (int ks = 0; ks < 2; ks++) {
#pragma unroll
        for (int qi = 0; qi < 4; qi++)
          l_acc[qi] = __builtin_amdgcn_mfma_f32_16x16x32_bf16(onesf, pbq[qi][ks].v, l_acc[qi], 0, 0, 0);
#pragma unroll
        for (int cb = 0; cb < 4; cb++) {
          const ushort* vb = &vbuf[sel][(cb * 16 + l15) * 128 + hb * 64];
          union { short8 v; uint2 d2[2]; } vv;
          vv.d2[0] = *(const uint2*)(vb + vo[ks][0]);
          vv.d2[1] = *(const uint2*)(vb + vo[ks][1]);
#pragma unroll
          for (int qi = 0; qi < 4; qi++)
            o_acc[qi][cb] = __builtin_amdgcn_mfma_f32_16x16x32_bf16(vv.v, pbq[qi][ks].v, o_acc[qi][cb], 0, 0, 0);
        }
      }
    }
    __syncthreads();
  }

  // ---- epilogue: O^T / l -> o[B][S][H*64] (bf16, packed 8B stores) ----
#pragma unroll
  for (int qi = 0; qi < 4; qi++) {
    const float inv = 1.f / l_acc[qi][0];
    ushort* ob = o + ((size_t)b * S_ + q0 + w * 64 + qi * 16 + l15) * DM + h * HD + 4 * g;
#pragma unroll
    for (int cb = 0; cb < 4; cb++) {
      uint2 st;
      st.x = cvt_pk_bf16(o_acc[qi][cb][0] * inv, o_acc[qi][cb][1] * inv);
      st.y = cvt_pk_bf16(o_acc[qi][cb][2] * inv, o_acc[qi][cb][3] * inv);
      *(uint2*)(ob + cb * 16) = st;
    }
  }
}

// ---------------- launch ----------------
extern "C" void kernel_launch(void* const* d_in, const int* in_sizes, int n_in,
                              void* d_out, int out_size, void* d_ws, size_t ws_size,
                              hipStream_t stream) {
  const float* Q  = (const float*)d_in[0];
  const float* K  = (const float*)d_in[1];
  const float* V  = (const float*)d_in[2];
  const float* Wq = (const float*)d_in[3];
  const float* bq = (const float*)d_in[4];
  const float* Wk = (const float*)d_in[5];
  const float* bk = (const float*)d_in[6];
  const float* Wv = (const float*)d_in[7];
  const float* bv = (const float*)d_in[8];
  const float* Wo = (const float*)d_in[9];
  const float* bo = (const float*)d_in[10];
  float* out = (float*)d_out;
  ushort* ws = (ushort*)d_ws;

  const size_t WN = (size_t)1024 * 1024;       // weight elems
  const size_t PN = (size_t)B_ * S_ * DM;      // activation elems (8.39M)
  ushort* wT  = ws;                             // wq/wk/wv/wo transposed, contiguous
  ushort* woT = ws + 3 * WN;
  ushort* qws = ws + 4 * WN;
  ushort* kws = qws + PN;
  ushort* ows = kws + PN;
  ushort* vt  = (ushort*)d_out;  // V^T scratch in d_out (bf16 16.8MB < fp32 33.5MB); overwritten by final GEMM

  transposeW4<<<dim3(256, 4), 256, 0, stream>>>(Wq, Wk, Wv, Wo, wT);

  // fused Q/K/V projections (bench-level winner per R7 post-mortem)
  gemm_qkv<<<dim3(64, 8, 3), 256, 0, stream>>>(Q, K, V, wT, bq, bk, bv, qws, kws, vt);

  attn<<<BH * 8, 256, 0, stream>>>(qws, kws, vt, ows);

  gemm_out<<<dim3(64, 8), 256, 0, stream>>>(ows, woT, bo, out);
}